// Round 1
// baseline (2206.325 us; speedup 1.0000x reference)
//
#include <hip/hip_runtime.h>
#include <hip/hip_bf16.h>

#define N_NODES   100000
#define N_EDGES   1600000
#define F_IN      64
#define HID       64
#define N_CLASSES 45
#define N_GRAPHS  256
#define NBLK      391           // ceil(100000/256) for the scan
#define WT_STRIDE 68            // padded LDS stride for W^T (breaks 32-bank aliasing, keeps 16B align)

// ---------------- CSR build ----------------

__global__ void k_zero(int* cnt, int* gcnt) {
    int i = blockIdx.x * blockDim.x + threadIdx.x;
    if (i < N_NODES)  cnt[i]  = 0;
    if (i < N_GRAPHS) gcnt[i] = 0;
}

__global__ void k_count(const int* __restrict__ dst, int* __restrict__ cnt) {
    int e = blockIdx.x * blockDim.x + threadIdx.x;
    if (e < N_EDGES) atomicAdd(&cnt[dst[e]], 1);
}

__global__ void k_blksum(const int* __restrict__ cnt, int* __restrict__ blk) {
    __shared__ int s[256];
    int t = threadIdx.x;
    int i = blockIdx.x * 256 + t;
    s[t] = (i < N_NODES) ? cnt[i] : 0;
    __syncthreads();
    for (int o = 128; o > 0; o >>= 1) {
        if (t < o) s[t] += s[t + o];
        __syncthreads();
    }
    if (t == 0) blk[blockIdx.x] = s[0];
}

__global__ void k_scanblk(int* blk) {
    if (threadIdx.x == 0) {
        int run = 0;
        for (int i = 0; i < NBLK; i++) { int v = blk[i]; blk[i] = run; run += v; }
    }
}

__global__ void k_scanfinal(const int* __restrict__ cnt, const int* __restrict__ blkoff,
                            int* __restrict__ off, int* __restrict__ wr) {
    __shared__ int s[256];
    int t = threadIdx.x;
    int i = blockIdx.x * 256 + t;
    int v = (i < N_NODES) ? cnt[i] : 0;
    s[t] = v;
    __syncthreads();
    for (int o = 1; o < 256; o <<= 1) {
        int x = (t >= o) ? s[t - o] : 0;
        __syncthreads();
        if (t >= o) s[t] += x;
        __syncthreads();
    }
    int excl = s[t] - v + blkoff[blockIdx.x];
    if (i < N_NODES) { off[i] = excl; wr[i] = excl; }
    if (i == 0 && blockIdx.x == 0) off[N_NODES] = N_EDGES;
}

__global__ void k_dinv(const int* __restrict__ cnt, float* __restrict__ dinv, float* __restrict__ dinv2) {
    int i = blockIdx.x * blockDim.x + threadIdx.x;
    if (i < N_NODES) {
        float d   = (float)(cnt[i] + 1);   // +1 self loop
        float inv = 1.0f / d;
        dinv2[i]  = inv;
        dinv[i]   = sqrtf(inv);
    }
}

__global__ void k_fill(const int* __restrict__ src, const int* __restrict__ dst,
                       const float* __restrict__ dinv, int* __restrict__ wr,
                       int* __restrict__ csr_src, float* __restrict__ csr_coef) {
    int e = blockIdx.x * blockDim.x + threadIdx.x;
    if (e < N_EDGES) {
        int d = dst[e], s = src[e];
        int p = atomicAdd(&wr[d], 1);
        csr_src[p]  = s;
        csr_coef[p] = dinv[s] * dinv[d];
    }
}

// ---------------- GEMM: H = relu?(in) @ W ; A = H*dinv2 + b ----------------
// block = 256 threads, tile = 64 rows x 64 cols.
template<bool RELU_IN>
__global__ __launch_bounds__(256) void k_gemm(const float* __restrict__ in, const float* __restrict__ W,
                                              const float* __restrict__ bias, const float* __restrict__ dinv2,
                                              float* __restrict__ Hout, float* __restrict__ Aout) {
    __shared__ float Wt[64 * WT_STRIDE];   // Wt[col][k], padded
    __shared__ float Xs[64 * 64];          // Xs[row][k]
    int t  = threadIdx.x;
    int nb = blockIdx.x * 64;              // first node of tile
    int rows = N_NODES - nb; if (rows > 64) rows = 64;

    // stage W transposed (coalesced global read)
    #pragma unroll
    for (int i = 0; i < 16; i++) {
        int idx = t + i * 256;             // idx = k*64 + c
        int k = idx >> 6, c = idx & 63;
        Wt[c * WT_STRIDE + k] = W[idx];
    }
    // stage X tile (float4, relu on load)
    const float4* xin = (const float4*)(in + (size_t)nb * 64);
    #pragma unroll
    for (int i = 0; i < 4; i++) {
        int v4 = t + i * 256;              // float4 index; 16 per row
        int r  = v4 >> 4;
        if (r < rows) {
            float4 x = xin[v4];
            if (RELU_IN) {
                x.x = fmaxf(x.x, 0.f); x.y = fmaxf(x.y, 0.f);
                x.z = fmaxf(x.z, 0.f); x.w = fmaxf(x.w, 0.f);
            }
            ((float4*)Xs)[v4] = x;
        }
    }
    __syncthreads();

    int col   = t & 63;
    int rbase = (t >> 6) * 16;             // each thread: 16 rows, 1 col
    float acc[16];
    #pragma unroll
    for (int r = 0; r < 16; r++) acc[r] = 0.f;

    const float4* wrow = (const float4*)(Wt + col * WT_STRIDE);
    #pragma unroll
    for (int k4 = 0; k4 < 16; k4++) {
        float4 w = wrow[k4];
        #pragma unroll
        for (int r = 0; r < 16; r++) {
            float4 x = ((const float4*)(Xs + (rbase + r) * 64))[k4];
            acc[r] += x.x * w.x + x.y * w.y + x.z * w.z + x.w * w.w;
        }
    }

    float bcol = bias[col];
    #pragma unroll
    for (int r = 0; r < 16; r++) {
        int node = nb + rbase + r;
        if (node < N_NODES) {
            float h = acc[r];
            Hout[(size_t)node * 64 + col] = h;
            Aout[(size_t)node * 64 + col] = h * dinv2[node] + bcol;  // self-loop + bias init
        }
    }
}

// ---------------- Aggregation (gather): A[i] += sum_j coef_j * H[src_j] ----------------
// one wave per node, lane = feature
__global__ __launch_bounds__(256) void k_agg(const float* __restrict__ Hbuf, const int* __restrict__ off,
                                             const int* __restrict__ csr_src, const float* __restrict__ csr_coef,
                                             float* __restrict__ Abuf) {
    int wv   = __builtin_amdgcn_readfirstlane(threadIdx.x >> 6);
    int lane = threadIdx.x & 63;
    int node = blockIdx.x * 4 + wv;
    if (node >= N_NODES) return;
    int beg = off[node], end = off[node + 1];
    float acc = Abuf[(size_t)node * 64 + lane];
    int j = beg;
    for (; j + 1 < end; j += 2) {
        int   s0 = csr_src[j],     s1 = csr_src[j + 1];
        float c0 = csr_coef[j],    c1 = csr_coef[j + 1];
        float h0 = Hbuf[(size_t)s0 * 64 + lane];
        float h1 = Hbuf[(size_t)s1 * 64 + lane];
        acc += h0 * c0;
        acc += h1 * c1;
    }
    if (j < end) {
        int   s0 = csr_src[j];
        float c0 = csr_coef[j];
        acc += Hbuf[(size_t)s0 * 64 + lane] * c0;
    }
    Abuf[(size_t)node * 64 + lane] = acc;
}

// ---------------- Pooling + classifier ----------------

__global__ void k_gcnt(const int* __restrict__ batch, int* __restrict__ gcnt) {
    int i = blockIdx.x * blockDim.x + threadIdx.x;
    if (i < N_NODES) atomicAdd(&gcnt[batch[i]], 1);
}

__global__ void k_goff(const int* __restrict__ gcnt, int* __restrict__ goff) {
    if (threadIdx.x == 0) {
        int run = 0;
        for (int g = 0; g < N_GRAPHS; g++) { goff[g] = run; run += gcnt[g]; }
        goff[N_GRAPHS] = run;
    }
}

__global__ __launch_bounds__(64) void k_pool(const float* __restrict__ A, const int* __restrict__ goff,
                                             const float* __restrict__ Wl, const float* __restrict__ bl,
                                             float* __restrict__ out) {
    __shared__ float pooled[64];
    int g = blockIdx.x;
    int f = threadIdx.x;
    int beg = goff[g], end = goff[g + 1];
    float acc = 0.f;
    for (int i = beg; i < end; i++) acc += A[(size_t)i * 64 + f];
    float cntf = (float)(end - beg);
    pooled[f] = acc / fmaxf(cntf, 1.0f);
    __syncthreads();
    if (f < N_CLASSES) {
        float o = bl[f];
        #pragma unroll
        for (int k = 0; k < HID; k++) o += pooled[k] * Wl[k * N_CLASSES + f];
        out[g * N_CLASSES + f] = o;
    }
}

// ---------------- launch ----------------

extern "C" void kernel_launch(void* const* d_in, const int* in_sizes, int n_in,
                              void* d_out, int out_size, void* d_ws, size_t ws_size,
                              hipStream_t stream) {
    const float* x     = (const float*)d_in[0];
    const int*   eidx  = (const int*)  d_in[1];
    const int*   batch = (const int*)  d_in[2];
    const float* W1 = (const float*)d_in[3];
    const float* b1 = (const float*)d_in[4];
    const float* W2 = (const float*)d_in[5];
    const float* b2 = (const float*)d_in[6];
    const float* W3 = (const float*)d_in[7];
    const float* b3 = (const float*)d_in[8];
    const float* Wl = (const float*)d_in[9];
    const float* bl = (const float*)d_in[10];
    const int* src = eidx;
    const int* dst = eidx + N_EDGES;

    char* p = (char*)d_ws;
    auto alloc = [&](size_t bytes) -> void* {
        void* r = (void*)p;
        p += (bytes + 255) & ~(size_t)255;
        return r;
    };
    int*   cnt      = (int*)  alloc((size_t)N_NODES * 4);
    int*   off      = (int*)  alloc((size_t)(N_NODES + 1) * 4);
    int*   wr       = (int*)  alloc((size_t)N_NODES * 4);
    int*   blk      = (int*)  alloc((size_t)NBLK * 4);
    float* dinv     = (float*)alloc((size_t)N_NODES * 4);
    float* dinv2    = (float*)alloc((size_t)N_NODES * 4);
    int*   csr_src  = (int*)  alloc((size_t)N_EDGES * 4);
    float* csr_coef = (float*)alloc((size_t)N_EDGES * 4);
    float* Hb       = (float*)alloc((size_t)N_NODES * 64 * 4);
    float* Ab       = (float*)alloc((size_t)N_NODES * 64 * 4);
    float* Bb       = (float*)alloc((size_t)N_NODES * 64 * 4);
    int*   gcnt     = (int*)  alloc((size_t)N_GRAPHS * 4);
    int*   goff     = (int*)  alloc((size_t)(N_GRAPHS + 1) * 4);

    const int eblocks = (N_EDGES + 255) / 256;
    const int nblocks = (N_NODES + 255) / 256;
    const int gemm_grid = (N_NODES + 63) / 64;     // 1563
    const int agg_grid  = (N_NODES + 3) / 4;       // 25000

    // CSR build (depends only on edge structure; reused by all 3 layers)
    k_zero<<<nblocks, 256, 0, stream>>>(cnt, gcnt);
    k_count<<<eblocks, 256, 0, stream>>>(dst, cnt);
    k_blksum<<<NBLK, 256, 0, stream>>>(cnt, blk);
    k_scanblk<<<1, 64, 0, stream>>>(blk);
    k_scanfinal<<<NBLK, 256, 0, stream>>>(cnt, blk, off, wr);
    k_dinv<<<nblocks, 256, 0, stream>>>(cnt, dinv, dinv2);
    k_fill<<<eblocks, 256, 0, stream>>>(src, dst, dinv, wr, csr_src, csr_coef);

    // layer 1: in = x
    k_gemm<false><<<gemm_grid, 256, 0, stream>>>(x,  W1, b1, dinv2, Hb, Ab);
    k_agg<<<agg_grid, 256, 0, stream>>>(Hb, off, csr_src, csr_coef, Ab);
    // layer 2: in = relu(Ab)
    k_gemm<true><<<gemm_grid, 256, 0, stream>>>(Ab, W2, b2, dinv2, Hb, Bb);
    k_agg<<<agg_grid, 256, 0, stream>>>(Hb, off, csr_src, csr_coef, Bb);
    // layer 3: in = relu(Bb)
    k_gemm<true><<<gemm_grid, 256, 0, stream>>>(Bb, W3, b3, dinv2, Hb, Ab);
    k_agg<<<agg_grid, 256, 0, stream>>>(Hb, off, csr_src, csr_coef, Ab);

    // pooling + classifier
    k_gcnt<<<nblocks, 256, 0, stream>>>(batch, gcnt);
    k_goff<<<1, 64, 0, stream>>>(gcnt, goff);
    k_pool<<<N_GRAPHS, 64, 0, stream>>>(Ab, goff, Wl, bl, (float*)d_out);
}

// Round 2
// 625.021 us; speedup vs baseline: 3.5300x; 3.5300x over previous
//
#include <hip/hip_runtime.h>
#include <hip/hip_bf16.h>

#define N_NODES   100000
#define N_EDGES   1600000
#define F_IN      64
#define HID       64
#define N_CLASSES 45
#define N_GRAPHS  256
#define NBLK      391           // ceil(100000/256) for the node-degree scan

__device__ __forceinline__ float rl_f(float v, int k) {
    return __uint_as_float(__builtin_amdgcn_readlane(__float_as_uint(v), k));
}
__device__ __forceinline__ int rl_i(int v, int k) {
    return __builtin_amdgcn_readlane(v, k);
}

// ---------------- CSR build ----------------

__global__ void k_count(const int* __restrict__ dst, int* __restrict__ cnt) {
    int e = blockIdx.x * blockDim.x + threadIdx.x;
    if (e < N_EDGES) atomicAdd(&cnt[dst[e]], 1);
}

__global__ void k_blksum(const int* __restrict__ cnt, int* __restrict__ blk) {
    __shared__ int s[256];
    int t = threadIdx.x;
    int i = blockIdx.x * 256 + t;
    s[t] = (i < N_NODES) ? cnt[i] : 0;
    __syncthreads();
    for (int o = 128; o > 0; o >>= 1) {
        if (t < o) s[t] += s[t + o];
        __syncthreads();
    }
    if (t == 0) blk[blockIdx.x] = s[0];
}

// parallel exclusive scan of the 391 block sums (single block, 512 threads)
__global__ void k_scanblk(int* blk) {
    __shared__ int s[512];
    int t = threadIdx.x;
    int v = (t < NBLK) ? blk[t] : 0;
    s[t] = v;
    __syncthreads();
    for (int o = 1; o < 512; o <<= 1) {
        int x = (t >= o) ? s[t - o] : 0;
        __syncthreads();
        if (t >= o) s[t] += x;
        __syncthreads();
    }
    if (t < NBLK) blk[t] = s[t] - v;   // exclusive
}

__global__ void k_scanfinal(const int* __restrict__ cnt, const int* __restrict__ blkoff,
                            int* __restrict__ off, int* __restrict__ wr) {
    __shared__ int s[256];
    int t = threadIdx.x;
    int i = blockIdx.x * 256 + t;
    int v = (i < N_NODES) ? cnt[i] : 0;
    s[t] = v;
    __syncthreads();
    for (int o = 1; o < 256; o <<= 1) {
        int x = (t >= o) ? s[t - o] : 0;
        __syncthreads();
        if (t >= o) s[t] += x;
        __syncthreads();
    }
    int excl = s[t] - v + blkoff[blockIdx.x];
    if (i < N_NODES) { off[i] = excl; wr[i] = excl; }
    if (i == 0 && blockIdx.x == 0) off[N_NODES] = N_EDGES;
}

__global__ void k_dinv(const int* __restrict__ cnt, float* __restrict__ dinv, float* __restrict__ dinv2) {
    int i = blockIdx.x * blockDim.x + threadIdx.x;
    if (i < N_NODES) {
        float d   = (float)(cnt[i] + 1);   // +1 self loop
        float inv = 1.0f / d;
        dinv2[i]  = inv;
        dinv[i]   = sqrtf(inv);
    }
}

__global__ void k_fill(const int* __restrict__ src, const int* __restrict__ dst,
                       const float* __restrict__ dinv, int* __restrict__ wr,
                       int* __restrict__ csr_src, float* __restrict__ csr_coef) {
    int e = blockIdx.x * blockDim.x + threadIdx.x;
    if (e < N_EDGES) {
        int d = dst[e], s = src[e];
        int p = atomicAdd(&wr[d], 1);
        csr_src[p]  = s;
        csr_coef[p] = dinv[s] * dinv[d];
    }
}

// graph segment offsets straight from the sorted batch array (no atomics/scan)
__global__ void k_goff(const int* __restrict__ batch, int* __restrict__ goff) {
    int i = blockIdx.x * blockDim.x + threadIdx.x;
    if (i >= N_NODES) return;
    int b = batch[i];
    if (i == 0) {
        for (int g = 0; g <= b; g++) goff[g] = 0;
    } else {
        int pb = batch[i - 1];
        for (int g = pb + 1; g <= b; g++) goff[g] = i;
    }
    if (i == N_NODES - 1) {
        for (int g = b + 1; g <= N_GRAPHS; g++) goff[g] = N_NODES;
    }
}

// ---------------- GEMM: H = relu?(in) @ W ----------------
// wave-per-row, lane = output col. W column in 64 VGPRs/lane; x-row broadcast
// via v_readlane (compile-time lane idx -> SGPR operand into v_fmac).
// block = 256 (4 waves), 8 rows per wave -> 32 rows/block, grid 3125 exact.
template<bool RELU_IN>
__global__ __launch_bounds__(256, 4) void k_gemm(const float* __restrict__ in,
                                                 const float* __restrict__ W,
                                                 float* __restrict__ Hout) {
    int lane = threadIdx.x & 63;
    int wv   = threadIdx.x >> 6;
    float Wreg[64];
    #pragma unroll
    for (int k = 0; k < 64; k++) Wreg[k] = W[k * 64 + lane];

    int base = blockIdx.x * 32 + wv * 8;
    #pragma unroll 2
    for (int r = 0; r < 8; r++) {
        int row = base + r;                       // grid sized exactly, no guard needed
        float xv = in[(size_t)row * 64 + lane];
        if (RELU_IN) xv = fmaxf(xv, 0.f);
        float acc = 0.f;
        #pragma unroll
        for (int k = 0; k < 64; k++)
            acc = fmaf(rl_f(xv, k), Wreg[k], acc);
        Hout[(size_t)row * 64 + lane] = acc;
    }
}

// ---------------- Aggregation (gather) ----------------
// A[i] = b + H[i]*dinv2[i] + sum_j coef_j * H[src_j]
// one wave per node, lane = feature. Edge indices/coefs chunk-loaded 64 at a
// time (one coalesced load), broadcast via readlane, 4 gathers in flight.
__global__ __launch_bounds__(256, 8) void k_agg(const float* __restrict__ Hbuf,
                                                const int* __restrict__ off,
                                                const int* __restrict__ csr_src,
                                                const float* __restrict__ csr_coef,
                                                const float* __restrict__ dinv2,
                                                const float* __restrict__ bias,
                                                float* __restrict__ Abuf) {
    int wv   = threadIdx.x >> 6;
    int lane = threadIdx.x & 63;
    int node = blockIdx.x * 4 + wv;
    if (node >= N_NODES) return;

    int beg = off[node], end = off[node + 1];
    float h    = Hbuf[(size_t)node * 64 + lane];
    float acc  = fmaf(h, dinv2[node], bias[lane]);
    float acc2 = 0.f;

    for (int cb = beg; cb < end; cb += 64) {
        int rem = end - cb; if (rem > 64) rem = 64;
        int   ii = 0; float cc = 0.f;
        if (lane < rem) { ii = csr_src[cb + lane]; cc = csr_coef[cb + lane]; }
        int j = 0;
        for (; j + 4 <= rem; j += 4) {
            int   s0 = rl_i(ii, j),     s1 = rl_i(ii, j + 1);
            int   s2 = rl_i(ii, j + 2), s3 = rl_i(ii, j + 3);
            float c0 = rl_f(cc, j),     c1 = rl_f(cc, j + 1);
            float c2 = rl_f(cc, j + 2), c3 = rl_f(cc, j + 3);
            float h0 = Hbuf[(size_t)s0 * 64 + lane];
            float h1 = Hbuf[(size_t)s1 * 64 + lane];
            float h2 = Hbuf[(size_t)s2 * 64 + lane];
            float h3 = Hbuf[(size_t)s3 * 64 + lane];
            acc  = fmaf(h0, c0, acc);
            acc2 = fmaf(h1, c1, acc2);
            acc  = fmaf(h2, c2, acc);
            acc2 = fmaf(h3, c3, acc2);
        }
        for (; j < rem; j++) {
            int   s0 = rl_i(ii, j);
            float c0 = rl_f(cc, j);
            acc = fmaf(Hbuf[(size_t)s0 * 64 + lane], c0, acc);
        }
    }
    Abuf[(size_t)node * 64 + lane] = acc + acc2;
}

// ---------------- Pooling + classifier ----------------

__global__ __launch_bounds__(64) void k_pool(const float* __restrict__ A, const int* __restrict__ goff,
                                             const float* __restrict__ Wl, const float* __restrict__ bl,
                                             float* __restrict__ out) {
    __shared__ float pooled[64];
    int g = blockIdx.x;
    int f = threadIdx.x;
    int beg = goff[g], end = goff[g + 1];
    float acc = 0.f;
    for (int i = beg; i < end; i++) acc += A[(size_t)i * 64 + f];
    float cntf = (float)(end - beg);
    pooled[f] = acc / fmaxf(cntf, 1.0f);
    __syncthreads();
    if (f < N_CLASSES) {
        float o = bl[f];
        #pragma unroll
        for (int k = 0; k < HID; k++) o += pooled[k] * Wl[k * N_CLASSES + f];
        out[g * N_CLASSES + f] = o;
    }
}

// ---------------- launch ----------------

extern "C" void kernel_launch(void* const* d_in, const int* in_sizes, int n_in,
                              void* d_out, int out_size, void* d_ws, size_t ws_size,
                              hipStream_t stream) {
    const float* x     = (const float*)d_in[0];
    const int*   eidx  = (const int*)  d_in[1];
    const int*   batch = (const int*)  d_in[2];
    const float* W1 = (const float*)d_in[3];
    const float* b1 = (const float*)d_in[4];
    const float* W2 = (const float*)d_in[5];
    const float* b2 = (const float*)d_in[6];
    const float* W3 = (const float*)d_in[7];
    const float* b3 = (const float*)d_in[8];
    const float* Wl = (const float*)d_in[9];
    const float* bl = (const float*)d_in[10];
    const int* src = eidx;
    const int* dst = eidx + N_EDGES;

    char* p = (char*)d_ws;
    auto alloc = [&](size_t bytes) -> void* {
        void* r = (void*)p;
        p += (bytes + 255) & ~(size_t)255;
        return r;
    };
    int*   cnt      = (int*)  alloc((size_t)N_NODES * 4);
    int*   off      = (int*)  alloc((size_t)(N_NODES + 1) * 4);
    int*   wr       = (int*)  alloc((size_t)N_NODES * 4);
    int*   blk      = (int*)  alloc((size_t)NBLK * 4);
    float* dinv     = (float*)alloc((size_t)N_NODES * 4);
    float* dinv2    = (float*)alloc((size_t)N_NODES * 4);
    int*   csr_src  = (int*)  alloc((size_t)N_EDGES * 4);
    float* csr_coef = (float*)alloc((size_t)N_EDGES * 4);
    float* Hb       = (float*)alloc((size_t)N_NODES * 64 * 4);
    float* Ab       = (float*)alloc((size_t)N_NODES * 64 * 4);
    float* Bb       = (float*)alloc((size_t)N_NODES * 64 * 4);
    int*   goff     = (int*)  alloc((size_t)(N_GRAPHS + 1) * 4);

    const int eblocks = (N_EDGES + 255) / 256;
    const int nblocks = (N_NODES + 255) / 256;
    const int gemm_grid = N_NODES / 32;            // 3125, exact
    const int agg_grid  = (N_NODES + 3) / 4;       // 25000

    // CSR build (structure only; reused by all 3 layers)
    hipMemsetAsync(cnt, 0, (size_t)N_NODES * 4, stream);
    k_count<<<eblocks, 256, 0, stream>>>(dst, cnt);
    k_blksum<<<NBLK, 256, 0, stream>>>(cnt, blk);
    k_scanblk<<<1, 512, 0, stream>>>(blk);
    k_scanfinal<<<NBLK, 256, 0, stream>>>(cnt, blk, off, wr);
    k_dinv<<<nblocks, 256, 0, stream>>>(cnt, dinv, dinv2);
    k_fill<<<eblocks, 256, 0, stream>>>(src, dst, dinv, wr, csr_src, csr_coef);
    k_goff<<<nblocks, 256, 0, stream>>>(batch, goff);

    // layer 1
    k_gemm<false><<<gemm_grid, 256, 0, stream>>>(x,  W1, Hb);
    k_agg<<<agg_grid, 256, 0, stream>>>(Hb, off, csr_src, csr_coef, dinv2, b1, Ab);
    // layer 2
    k_gemm<true><<<gemm_grid, 256, 0, stream>>>(Ab, W2, Hb);
    k_agg<<<agg_grid, 256, 0, stream>>>(Hb, off, csr_src, csr_coef, dinv2, b2, Bb);
    // layer 3
    k_gemm<true><<<gemm_grid, 256, 0, stream>>>(Bb, W3, Hb);
    k_agg<<<agg_grid, 256, 0, stream>>>(Hb, off, csr_src, csr_coef, dinv2, b3, Ab);

    // pooling + classifier
    k_pool<<<N_GRAPHS, 64, 0, stream>>>(Ab, goff, Wl, bl, (float*)d_out);
}

// Round 3
// 541.854 us; speedup vs baseline: 4.0718x; 1.1535x over previous
//
#include <hip/hip_runtime.h>
#include <hip/hip_bf16.h>

#define N_NODES   100000
#define N_EDGES   1600000
#define F_IN      64
#define HID       64
#define N_CLASSES 45
#define N_GRAPHS  256
#define NBLK      391           // ceil(100000/256) for the node-degree scan

__device__ __forceinline__ float rl_f(float v, int k) {
    return __uint_as_float(__builtin_amdgcn_readlane(__float_as_uint(v), k));
}
__device__ __forceinline__ int rl_i(int v, int k) {
    return __builtin_amdgcn_readlane(v, k);
}

// ---------------- CSR build ----------------

__global__ void k_count(const int* __restrict__ dst, int* __restrict__ cnt) {
    int e4 = blockIdx.x * blockDim.x + threadIdx.x;
    if (e4 < N_EDGES / 4) {
        int4 d = ((const int4*)dst)[e4];
        atomicAdd(&cnt[d.x], 1);
        atomicAdd(&cnt[d.y], 1);
        atomicAdd(&cnt[d.z], 1);
        atomicAdd(&cnt[d.w], 1);
    }
}

__global__ void k_blksum(const int* __restrict__ cnt, int* __restrict__ blk) {
    __shared__ int s[256];
    int t = threadIdx.x;
    int i = blockIdx.x * 256 + t;
    s[t] = (i < N_NODES) ? cnt[i] : 0;
    __syncthreads();
    for (int o = 128; o > 0; o >>= 1) {
        if (t < o) s[t] += s[t + o];
        __syncthreads();
    }
    if (t == 0) blk[blockIdx.x] = s[0];
}

// parallel exclusive scan of the 391 block sums (single block, 512 threads)
__global__ void k_scanblk(int* blk) {
    __shared__ int s[512];
    int t = threadIdx.x;
    int v = (t < NBLK) ? blk[t] : 0;
    s[t] = v;
    __syncthreads();
    for (int o = 1; o < 512; o <<= 1) {
        int x = (t >= o) ? s[t - o] : 0;
        __syncthreads();
        if (t >= o) s[t] += x;
        __syncthreads();
    }
    if (t < NBLK) blk[t] = s[t] - v;   // exclusive
}

// per-node exclusive offsets + dinv/dinv2 (fused degree math)
__global__ void k_scanfinal(const int* __restrict__ cnt, const int* __restrict__ blkoff,
                            int* __restrict__ off, int* __restrict__ wr,
                            float* __restrict__ dinv, float* __restrict__ dinv2) {
    __shared__ int s[256];
    int t = threadIdx.x;
    int i = blockIdx.x * 256 + t;
    int v = (i < N_NODES) ? cnt[i] : 0;
    s[t] = v;
    __syncthreads();
    for (int o = 1; o < 256; o <<= 1) {
        int x = (t >= o) ? s[t - o] : 0;
        __syncthreads();
        if (t >= o) s[t] += x;
        __syncthreads();
    }
    int excl = s[t] - v + blkoff[blockIdx.x];
    if (i < N_NODES) {
        off[i] = excl; wr[i] = excl;
        float d   = (float)(v + 1);        // +1 self loop
        float inv = 1.0f / d;
        dinv2[i]  = inv;
        dinv[i]   = sqrtf(inv);
    }
    if (i == 0 && blockIdx.x == 0) off[N_NODES] = N_EDGES;
}

// scatter edges into CSR; payload interleaved (src, coef) -> ONE 8B write/edge
__global__ void k_fill(const int* __restrict__ src, const int* __restrict__ dst,
                       const float* __restrict__ dinv, int* __restrict__ wr,
                       int2* __restrict__ csr) {
    int e4 = blockIdx.x * blockDim.x + threadIdx.x;
    if (e4 >= N_EDGES / 4) return;
    int4 d4 = ((const int4*)dst)[e4];
    int4 s4 = ((const int4*)src)[e4];
    {
        int p = atomicAdd(&wr[d4.x], 1);
        csr[p] = make_int2(s4.x, __float_as_int(dinv[s4.x] * dinv[d4.x]));
    }
    {
        int p = atomicAdd(&wr[d4.y], 1);
        csr[p] = make_int2(s4.y, __float_as_int(dinv[s4.y] * dinv[d4.y]));
    }
    {
        int p = atomicAdd(&wr[d4.z], 1);
        csr[p] = make_int2(s4.z, __float_as_int(dinv[s4.z] * dinv[d4.z]));
    }
    {
        int p = atomicAdd(&wr[d4.w], 1);
        csr[p] = make_int2(s4.w, __float_as_int(dinv[s4.w] * dinv[d4.w]));
    }
}

// graph segment offsets straight from the sorted batch array (no atomics/scan)
__global__ void k_goff(const int* __restrict__ batch, int* __restrict__ goff) {
    int i = blockIdx.x * blockDim.x + threadIdx.x;
    if (i >= N_NODES) return;
    int b = batch[i];
    if (i == 0) {
        for (int g = 0; g <= b; g++) goff[g] = 0;
    } else {
        int pb = batch[i - 1];
        for (int g = pb + 1; g <= b; g++) goff[g] = i;
    }
    if (i == N_NODES - 1) {
        for (int g = b + 1; g <= N_GRAPHS; g++) goff[g] = N_NODES;
    }
}

// ---------------- GEMM: H = relu?(in) @ W ----------------
// wave-per-row, lane = output col. W column in 64 VGPRs/lane; x-row broadcast
// via v_readlane (compile-time lane idx -> SGPR operand into v_fmac).
template<bool RELU_IN>
__global__ __launch_bounds__(256, 4) void k_gemm(const float* __restrict__ in,
                                                 const float* __restrict__ W,
                                                 float* __restrict__ Hout) {
    int lane = threadIdx.x & 63;
    int wv   = threadIdx.x >> 6;
    float Wreg[64];
    #pragma unroll
    for (int k = 0; k < 64; k++) Wreg[k] = W[k * 64 + lane];

    int base = blockIdx.x * 32 + wv * 8;
    #pragma unroll 2
    for (int r = 0; r < 8; r++) {
        int row = base + r;                       // grid sized exactly, no guard needed
        float xv = in[(size_t)row * 64 + lane];
        if (RELU_IN) xv = fmaxf(xv, 0.f);
        float acc = 0.f;
        #pragma unroll
        for (int k = 0; k < 64; k++)
            acc = fmaf(rl_f(xv, k), Wreg[k], acc);
        Hout[(size_t)row * 64 + lane] = acc;
    }
}

// ---------------- Aggregation (gather) ----------------
// A[i] = b + H[i]*dinv2[i] + sum_j coef_j * H[src_j]
// one wave per node, lane = feature. Edge (src,coef) pairs chunk-loaded 64 at
// a time (one coalesced int2 load), broadcast via readlane, 4 gathers in flight.
__global__ __launch_bounds__(256, 8) void k_agg(const float* __restrict__ Hbuf,
                                                const int* __restrict__ off,
                                                const int2* __restrict__ csr,
                                                const float* __restrict__ dinv2,
                                                const float* __restrict__ bias,
                                                float* __restrict__ Abuf) {
    int wv   = threadIdx.x >> 6;
    int lane = threadIdx.x & 63;
    int node = blockIdx.x * 4 + wv;
    if (node >= N_NODES) return;

    int beg = off[node], end = off[node + 1];
    float h    = Hbuf[(size_t)node * 64 + lane];
    float acc  = fmaf(h, dinv2[node], bias[lane]);
    float acc2 = 0.f;

    for (int cb = beg; cb < end; cb += 64) {
        int rem = end - cb; if (rem > 64) rem = 64;
        int ii = 0; int cc = 0;
        if (lane < rem) { int2 pc = csr[cb + lane]; ii = pc.x; cc = pc.y; }
        int j = 0;
        for (; j + 4 <= rem; j += 4) {
            int   s0 = rl_i(ii, j),     s1 = rl_i(ii, j + 1);
            int   s2 = rl_i(ii, j + 2), s3 = rl_i(ii, j + 3);
            float c0 = __int_as_float(rl_i(cc, j));
            float c1 = __int_as_float(rl_i(cc, j + 1));
            float c2 = __int_as_float(rl_i(cc, j + 2));
            float c3 = __int_as_float(rl_i(cc, j + 3));
            float h0 = Hbuf[(size_t)s0 * 64 + lane];
            float h1 = Hbuf[(size_t)s1 * 64 + lane];
            float h2 = Hbuf[(size_t)s2 * 64 + lane];
            float h3 = Hbuf[(size_t)s3 * 64 + lane];
            acc  = fmaf(h0, c0, acc);
            acc2 = fmaf(h1, c1, acc2);
            acc  = fmaf(h2, c2, acc);
            acc2 = fmaf(h3, c3, acc2);
        }
        for (; j < rem; j++) {
            int   s0 = rl_i(ii, j);
            float c0 = __int_as_float(rl_i(cc, j));
            acc = fmaf(Hbuf[(size_t)s0 * 64 + lane], c0, acc);
        }
    }
    Abuf[(size_t)node * 64 + lane] = acc + acc2;
}

// ---------------- Pooling + classifier ----------------
// one block (4 waves) per graph; waves split rows, LDS reduce, then 45-col GEMV
__global__ __launch_bounds__(256) void k_pool(const float* __restrict__ A, const int* __restrict__ goff,
                                              const float* __restrict__ Wl, const float* __restrict__ bl,
                                              float* __restrict__ out) {
    __shared__ float red[4][64];
    int g    = blockIdx.x;
    int wv   = threadIdx.x >> 6;
    int lane = threadIdx.x & 63;
    int beg = goff[g], end = goff[g + 1];

    float a0 = 0.f, a1 = 0.f;
    int i = beg + wv;
    for (; i + 4 < end; i += 8) {
        a0 += A[(size_t)i * 64 + lane];
        a1 += A[(size_t)(i + 4) * 64 + lane];
    }
    if (i < end) a0 += A[(size_t)i * 64 + lane];
    red[wv][lane] = a0 + a1;
    __syncthreads();
    if (wv == 0) {
        float s = red[0][lane] + red[1][lane] + red[2][lane] + red[3][lane];
        float cntf = (float)(end - beg);
        red[0][lane] = s / fmaxf(cntf, 1.0f);
    }
    __syncthreads();
    int f = threadIdx.x;
    if (f < N_CLASSES) {
        float o = bl[f];
        #pragma unroll
        for (int k = 0; k < HID; k++) o = fmaf(red[0][k], Wl[k * N_CLASSES + f], o);
        out[g * N_CLASSES + f] = o;
    }
}

// ---------------- launch ----------------

extern "C" void kernel_launch(void* const* d_in, const int* in_sizes, int n_in,
                              void* d_out, int out_size, void* d_ws, size_t ws_size,
                              hipStream_t stream) {
    const float* x     = (const float*)d_in[0];
    const int*   eidx  = (const int*)  d_in[1];
    const int*   batch = (const int*)  d_in[2];
    const float* W1 = (const float*)d_in[3];
    const float* b1 = (const float*)d_in[4];
    const float* W2 = (const float*)d_in[5];
    const float* b2 = (const float*)d_in[6];
    const float* W3 = (const float*)d_in[7];
    const float* b3 = (const float*)d_in[8];
    const float* Wl = (const float*)d_in[9];
    const float* bl = (const float*)d_in[10];
    const int* src = eidx;
    const int* dst = eidx + N_EDGES;

    char* p = (char*)d_ws;
    auto alloc = [&](size_t bytes) -> void* {
        void* r = (void*)p;
        p += (bytes + 255) & ~(size_t)255;
        return r;
    };
    int*   cnt   = (int*)  alloc((size_t)N_NODES * 4);
    int*   off   = (int*)  alloc((size_t)(N_NODES + 1) * 4);
    int*   wr    = (int*)  alloc((size_t)N_NODES * 4);
    int*   blk   = (int*)  alloc((size_t)NBLK * 4);
    float* dinv  = (float*)alloc((size_t)N_NODES * 4);
    float* dinv2 = (float*)alloc((size_t)N_NODES * 4);
    int2*  csr   = (int2*) alloc((size_t)N_EDGES * 8);
    float* Hb    = (float*)alloc((size_t)N_NODES * 64 * 4);
    float* Ab    = (float*)alloc((size_t)N_NODES * 64 * 4);
    float* Bb    = (float*)alloc((size_t)N_NODES * 64 * 4);
    int*   goff  = (int*)  alloc((size_t)(N_GRAPHS + 1) * 4);

    const int e4blocks = (N_EDGES / 4 + 255) / 256;
    const int nblocks  = (N_NODES + 255) / 256;
    const int gemm_grid = N_NODES / 32;            // 3125, exact
    const int agg_grid  = (N_NODES + 3) / 4;       // 25000

    // CSR build (structure only; reused by all 3 layers)
    hipMemsetAsync(cnt, 0, (size_t)N_NODES * 4, stream);
    k_count<<<e4blocks, 256, 0, stream>>>(dst, cnt);
    k_blksum<<<NBLK, 256, 0, stream>>>(cnt, blk);
    k_scanblk<<<1, 512, 0, stream>>>(blk);
    k_scanfinal<<<NBLK, 256, 0, stream>>>(cnt, blk, off, wr, dinv, dinv2);
    k_fill<<<e4blocks, 256, 0, stream>>>(src, dst, dinv, wr, csr);
    k_goff<<<nblocks, 256, 0, stream>>>(batch, goff);

    // layer 1
    k_gemm<false><<<gemm_grid, 256, 0, stream>>>(x,  W1, Hb);
    k_agg<<<agg_grid, 256, 0, stream>>>(Hb, off, csr, dinv2, b1, Ab);
    // layer 2
    k_gemm<true><<<gemm_grid, 256, 0, stream>>>(Ab, W2, Hb);
    k_agg<<<agg_grid, 256, 0, stream>>>(Hb, off, csr, dinv2, b2, Bb);
    // layer 3
    k_gemm<true><<<gemm_grid, 256, 0, stream>>>(Bb, W3, Hb);
    k_agg<<<agg_grid, 256, 0, stream>>>(Hb, off, csr, dinv2, b3, Ab);

    // pooling + classifier
    k_pool<<<N_GRAPHS, 256, 0, stream>>>(Ab, goff, Wl, bl, (float*)d_out);
}

// Round 4
// 461.463 us; speedup vs baseline: 4.7812x; 1.1742x over previous
//
#include <hip/hip_runtime.h>
#include <hip/hip_bf16.h>

#define N_NODES   100000
#define N_EDGES   1600000
#define F_IN      64
#define HID       64
#define N_CLASSES 45
#define N_GRAPHS  256
#define SB        98          // super-buckets: bucket = dst >> 10 (0..97)
#define CHUNK     8192        // edges per scatter/hist workgroup
#define NCHUNK    196         // ceil(N_EDGES / CHUNK)

__device__ __forceinline__ float rl_f(float v, int k) {
    return __uint_as_float(__builtin_amdgcn_readlane(__float_as_uint(v), k));
}
__device__ __forceinline__ int rl_i(int v, int k) {
    return __builtin_amdgcn_readlane(v, k);
}

// ---------------- CSR build: bucket counting sort ----------------

// super-bucket histogram (LDS-staged, 98 global atomics per WG)
__global__ __launch_bounds__(256) void k_hist(const int* __restrict__ dst, int* __restrict__ bcnt) {
    __shared__ int h[SB];
    int t = threadIdx.x;
    if (t < SB) h[t] = 0;
    __syncthreads();
    int base4 = blockIdx.x * (CHUNK / 4);
    #pragma unroll
    for (int i = 0; i < CHUNK / 1024; i++) {
        int e4 = base4 + i * 256 + t;
        if (e4 < N_EDGES / 4) {
            int4 d = ((const int4*)dst)[e4];
            atomicAdd(&h[d.x >> 10], 1);
            atomicAdd(&h[d.y >> 10], 1);
            atomicAdd(&h[d.z >> 10], 1);
            atomicAdd(&h[d.w >> 10], 1);
        }
    }
    __syncthreads();
    if (t < SB && h[t] > 0) atomicAdd(&bcnt[t], h[t]);
}

// exclusive scan of 98 bucket counts -> bbase, init bcur
__global__ __launch_bounds__(128) void k_bscan(const int* __restrict__ bcnt,
                                               int* __restrict__ bbase, int* __restrict__ bcur) {
    __shared__ int s[128];
    int t = threadIdx.x;
    int v = (t < SB) ? bcnt[t] : 0;
    s[t] = v;
    __syncthreads();
    for (int o = 1; o < 128; o <<= 1) {
        int x = (t >= o) ? s[t - o] : 0;
        __syncthreads();
        if (t >= o) s[t] += x;
        __syncthreads();
    }
    if (t < SB) { int ex = s[t] - v; bbase[t] = ex; bcur[t] = ex; }
    if (t == 0) bbase[SB] = N_EDGES;
}

// multisplit: stage 8192 edges in LDS by bucket, flush contiguous runs.
// payload: src(17b) | dstLow(10b)<<17
__global__ __launch_bounds__(256) void k_scatter(const int* __restrict__ src, const int* __restrict__ dst,
                                                 int* __restrict__ bcur, int* __restrict__ binned) {
    __shared__ int stg[CHUNK];
    __shared__ int h[SB], lbase[SB], gbase[SB], cur[SB];
    __shared__ int ss[128];
    int t = threadIdx.x;
    if (t < SB) h[t] = 0;
    __syncthreads();
    int base4 = blockIdx.x * (CHUNK / 4);
    // phase 1: local histogram
    #pragma unroll
    for (int i = 0; i < CHUNK / 1024; i++) {
        int e4 = base4 + i * 256 + t;
        if (e4 < N_EDGES / 4) {
            int4 d = ((const int4*)dst)[e4];
            atomicAdd(&h[d.x >> 10], 1);
            atomicAdd(&h[d.y >> 10], 1);
            atomicAdd(&h[d.z >> 10], 1);
            atomicAdd(&h[d.w >> 10], 1);
        }
    }
    __syncthreads();
    // phase 2: local exclusive scan + global space reservation
    if (t < 128) ss[t] = (t < SB) ? h[t] : 0;
    __syncthreads();
    for (int o = 1; o < 128; o <<= 1) {
        int x = 0;
        if (t < 128 && t >= o) x = ss[t - o];
        __syncthreads();
        if (t < 128 && t >= o) ss[t] += x;
        __syncthreads();
    }
    if (t < SB) {
        int ex = ss[t] - h[t];
        lbase[t] = ex;
        cur[t]   = ex;
        gbase[t] = atomicAdd(&bcur[t], h[t]);
    }
    __syncthreads();
    // phase 3: re-read edges, scatter packed payload into LDS staging
    #pragma unroll
    for (int i = 0; i < CHUNK / 1024; i++) {
        int e4 = base4 + i * 256 + t;
        if (e4 < N_EDGES / 4) {
            int4 d  = ((const int4*)dst)[e4];
            int4 s4 = ((const int4*)src)[e4];
            int q;
            q = atomicAdd(&cur[d.x >> 10], 1); stg[q] = s4.x | ((d.x & 1023) << 17);
            q = atomicAdd(&cur[d.y >> 10], 1); stg[q] = s4.y | ((d.y & 1023) << 17);
            q = atomicAdd(&cur[d.z >> 10], 1); stg[q] = s4.z | ((d.z & 1023) << 17);
            q = atomicAdd(&cur[d.w >> 10], 1); stg[q] = s4.w | ((d.w & 1023) << 17);
        }
    }
    __syncthreads();
    // phase 4: flush each bucket's run contiguously (wave per bucket, round-robin)
    int wv = t >> 6, lane = t & 63;
    for (int b = wv; b < SB; b += 4) {
        int n = h[b], lb = lbase[b], gb = gbase[b];
        for (int i = lane; i < n; i += 64)
            binned[gb + i] = stg[lb + i];
    }
}

// per-bucket: node degrees -> dinv/dinv2 + exact CSR offsets (LDS scan)
__global__ __launch_bounds__(256) void k_bdeg(const int* __restrict__ binned, const int* __restrict__ bbase,
                                              int* __restrict__ off, float* __restrict__ dinv,
                                              float* __restrict__ dinv2) {
    __shared__ int h[1024];
    __shared__ int ts[256];
    int t = threadIdx.x;
    int b = blockIdx.x;
    int nb0 = b << 10;
    #pragma unroll
    for (int i = 0; i < 4; i++) h[t + i * 256] = 0;
    __syncthreads();
    int ebeg = bbase[b], eend = bbase[b + 1];
    for (int i = ebeg + t; i < eend; i += 256)
        atomicAdd(&h[binned[i] >> 17], 1);
    __syncthreads();
    int c0 = h[t * 4], c1 = h[t * 4 + 1], c2 = h[t * 4 + 2], c3 = h[t * 4 + 3];
    int tot = c0 + c1 + c2 + c3;
    ts[t] = tot;
    __syncthreads();
    for (int o = 1; o < 256; o <<= 1) {
        int x = (t >= o) ? ts[t - o] : 0;
        __syncthreads();
        if (t >= o) ts[t] += x;
        __syncthreads();
    }
    int ex = ts[t] - tot + ebeg;
    int n0 = nb0 + t * 4;
    if (n0 < N_NODES) {                      // bucket boundary is 4-aligned (last: 672 nodes)
        int   e[4] = { ex, ex + c0, ex + c0 + c1, ex + c0 + c1 + c2 };
        int   c[4] = { c0, c1, c2, c3 };
        #pragma unroll
        for (int i = 0; i < 4; i++) {
            off[n0 + i] = e[i];
            float inv = 1.0f / (float)(c[i] + 1);   // +1 self loop
            dinv2[n0 + i] = inv;
            dinv[n0 + i]  = sqrtf(inv);
        }
    }
    if (b == SB - 1 && t == 0) off[N_NODES] = N_EDGES;
}

// per-bucket CSR fill: LDS cursors, writes confined to the bucket's csr region
__global__ __launch_bounds__(256) void k_bfill(const int* __restrict__ binned, const int* __restrict__ bbase,
                                               const int* __restrict__ off, const float* __restrict__ dinv,
                                               int2* __restrict__ csr) {
    __shared__ int   cur[1024];
    __shared__ float dloc[1024];
    int t = threadIdx.x;
    int b = blockIdx.x;
    int nb0 = b << 10;
    #pragma unroll
    for (int i = 0; i < 4; i++) {
        int n = t + i * 256;
        int gn = nb0 + n;
        cur[n]  = (gn < N_NODES) ? off[gn]  : 0;
        dloc[n] = (gn < N_NODES) ? dinv[gn] : 0.f;
    }
    __syncthreads();
    int ebeg = bbase[b], eend = bbase[b + 1];
    for (int i = ebeg + t; i < eend; i += 256) {
        int p    = binned[i];
        int s    = p & 0x1FFFF;
        int dlow = p >> 17;
        float cs = dinv[s];                       // random 4B gather, L2-cached (400 KB table)
        int q = atomicAdd(&cur[dlow], 1);         // LDS atomic
        csr[q] = make_int2(s, __float_as_int(cs * dloc[dlow]));
    }
}

// graph segment offsets straight from the sorted batch array
__global__ void k_goff(const int* __restrict__ batch, int* __restrict__ goff) {
    int i = blockIdx.x * blockDim.x + threadIdx.x;
    if (i >= N_NODES) return;
    int b = batch[i];
    if (i == 0) {
        for (int g = 0; g <= b; g++) goff[g] = 0;
    } else {
        int pb = batch[i - 1];
        for (int g = pb + 1; g <= b; g++) goff[g] = i;
    }
    if (i == N_NODES - 1) {
        for (int g = b + 1; g <= N_GRAPHS; g++) goff[g] = N_NODES;
    }
}

// ---------------- GEMM: H = relu?(in) @ W ----------------
template<bool RELU_IN>
__global__ __launch_bounds__(256, 4) void k_gemm(const float* __restrict__ in,
                                                 const float* __restrict__ W,
                                                 float* __restrict__ Hout) {
    int lane = threadIdx.x & 63;
    int wv   = threadIdx.x >> 6;
    float Wreg[64];
    #pragma unroll
    for (int k = 0; k < 64; k++) Wreg[k] = W[k * 64 + lane];

    int base = blockIdx.x * 32 + wv * 8;
    #pragma unroll 2
    for (int r = 0; r < 8; r++) {
        int row = base + r;                       // grid exact, no guard
        float xv = in[(size_t)row * 64 + lane];
        if (RELU_IN) xv = fmaxf(xv, 0.f);
        float acc = 0.f;
        #pragma unroll
        for (int k = 0; k < 64; k++)
            acc = fmaf(rl_f(xv, k), Wreg[k], acc);
        Hout[(size_t)row * 64 + lane] = acc;
    }
}

// ---------------- Aggregation (gather) ----------------
__global__ __launch_bounds__(256, 8) void k_agg(const float* __restrict__ Hbuf,
                                                const int* __restrict__ off,
                                                const int2* __restrict__ csr,
                                                const float* __restrict__ dinv2,
                                                const float* __restrict__ bias,
                                                float* __restrict__ Abuf) {
    int wv   = threadIdx.x >> 6;
    int lane = threadIdx.x & 63;
    int node = blockIdx.x * 4 + wv;
    if (node >= N_NODES) return;

    int beg = off[node], end = off[node + 1];
    float h    = Hbuf[(size_t)node * 64 + lane];
    float acc  = fmaf(h, dinv2[node], bias[lane]);
    float acc2 = 0.f;

    for (int cb = beg; cb < end; cb += 64) {
        int rem = end - cb; if (rem > 64) rem = 64;
        int ii = 0; int cc = 0;
        if (lane < rem) { int2 pc = csr[cb + lane]; ii = pc.x; cc = pc.y; }
        int j = 0;
        for (; j + 4 <= rem; j += 4) {
            int   s0 = rl_i(ii, j),     s1 = rl_i(ii, j + 1);
            int   s2 = rl_i(ii, j + 2), s3 = rl_i(ii, j + 3);
            float c0 = __int_as_float(rl_i(cc, j));
            float c1 = __int_as_float(rl_i(cc, j + 1));
            float c2 = __int_as_float(rl_i(cc, j + 2));
            float c3 = __int_as_float(rl_i(cc, j + 3));
            float h0 = Hbuf[(size_t)s0 * 64 + lane];
            float h1 = Hbuf[(size_t)s1 * 64 + lane];
            float h2 = Hbuf[(size_t)s2 * 64 + lane];
            float h3 = Hbuf[(size_t)s3 * 64 + lane];
            acc  = fmaf(h0, c0, acc);
            acc2 = fmaf(h1, c1, acc2);
            acc  = fmaf(h2, c2, acc);
            acc2 = fmaf(h3, c3, acc2);
        }
        for (; j < rem; j++) {
            int   s0 = rl_i(ii, j);
            float c0 = __int_as_float(rl_i(cc, j));
            acc = fmaf(Hbuf[(size_t)s0 * 64 + lane], c0, acc);
        }
    }
    Abuf[(size_t)node * 64 + lane] = acc + acc2;
}

// ---------------- Pooling + classifier ----------------
__global__ __launch_bounds__(256) void k_pool(const float* __restrict__ A, const int* __restrict__ goff,
                                              const float* __restrict__ Wl, const float* __restrict__ bl,
                                              float* __restrict__ out) {
    __shared__ float red[4][64];
    int g    = blockIdx.x;
    int wv   = threadIdx.x >> 6;
    int lane = threadIdx.x & 63;
    int beg = goff[g], end = goff[g + 1];

    float a0 = 0.f, a1 = 0.f;
    int i = beg + wv;
    for (; i + 4 < end; i += 8) {
        a0 += A[(size_t)i * 64 + lane];
        a1 += A[(size_t)(i + 4) * 64 + lane];
    }
    if (i < end) a0 += A[(size_t)i * 64 + lane];
    red[wv][lane] = a0 + a1;
    __syncthreads();
    if (wv == 0) {
        float s = red[0][lane] + red[1][lane] + red[2][lane] + red[3][lane];
        float cntf = (float)(end - beg);
        red[0][lane] = s / fmaxf(cntf, 1.0f);
    }
    __syncthreads();
    int f = threadIdx.x;
    if (f < N_CLASSES) {
        float o = bl[f];
        #pragma unroll
        for (int k = 0; k < HID; k++) o = fmaf(red[0][k], Wl[k * N_CLASSES + f], o);
        out[g * N_CLASSES + f] = o;
    }
}

// ---------------- launch ----------------

extern "C" void kernel_launch(void* const* d_in, const int* in_sizes, int n_in,
                              void* d_out, int out_size, void* d_ws, size_t ws_size,
                              hipStream_t stream) {
    const float* x     = (const float*)d_in[0];
    const int*   eidx  = (const int*)  d_in[1];
    const int*   batch = (const int*)  d_in[2];
    const float* W1 = (const float*)d_in[3];
    const float* b1 = (const float*)d_in[4];
    const float* W2 = (const float*)d_in[5];
    const float* b2 = (const float*)d_in[6];
    const float* W3 = (const float*)d_in[7];
    const float* b3 = (const float*)d_in[8];
    const float* Wl = (const float*)d_in[9];
    const float* bl = (const float*)d_in[10];
    const int* src = eidx;
    const int* dst = eidx + N_EDGES;

    char* p = (char*)d_ws;
    auto alloc = [&](size_t bytes) -> void* {
        void* r = (void*)p;
        p += (bytes + 255) & ~(size_t)255;
        return r;
    };
    int*   off   = (int*)  alloc((size_t)(N_NODES + 1) * 4);
    float* dinv  = (float*)alloc((size_t)N_NODES * 4);
    float* dinv2 = (float*)alloc((size_t)N_NODES * 4);
    int2*  csr   = (int2*) alloc((size_t)N_EDGES * 8);
    float* Hb    = (float*)alloc((size_t)N_NODES * 64 * 4);
    float* Ab    = (float*)alloc((size_t)N_NODES * 64 * 4);
    float* Bb    = (float*)alloc((size_t)N_NODES * 64 * 4);
    int*   goff  = (int*)  alloc((size_t)(N_GRAPHS + 1) * 4);
    int*   bcnt  = (int*)  alloc((size_t)SB * 4);
    int*   bbase = (int*)  alloc((size_t)(SB + 1) * 4);
    int*   bcur  = (int*)  alloc((size_t)SB * 4);
    int*   binned = (int*)Hb;   // 6.4 MB scratch aliased onto Hb (used only pre-layer-1)

    const int nblocks   = (N_NODES + 255) / 256;
    const int gemm_grid = N_NODES / 32;            // 3125, exact
    const int agg_grid  = (N_NODES + 3) / 4;       // 25000

    // ---- CSR build (bucket counting sort; no per-node global atomics) ----
    hipMemsetAsync(bcnt, 0, (size_t)SB * 4, stream);
    k_hist   <<<NCHUNK, 256, 0, stream>>>(dst, bcnt);
    k_bscan  <<<1, 128, 0, stream>>>(bcnt, bbase, bcur);
    k_scatter<<<NCHUNK, 256, 0, stream>>>(src, dst, bcur, binned);
    k_bdeg   <<<SB, 256, 0, stream>>>(binned, bbase, off, dinv, dinv2);
    k_bfill  <<<SB, 256, 0, stream>>>(binned, bbase, off, dinv, csr);
    k_goff   <<<nblocks, 256, 0, stream>>>(batch, goff);

    // layer 1
    k_gemm<false><<<gemm_grid, 256, 0, stream>>>(x,  W1, Hb);
    k_agg<<<agg_grid, 256, 0, stream>>>(Hb, off, csr, dinv2, b1, Ab);
    // layer 2
    k_gemm<true><<<gemm_grid, 256, 0, stream>>>(Ab, W2, Hb);
    k_agg<<<agg_grid, 256, 0, stream>>>(Hb, off, csr, dinv2, b2, Bb);
    // layer 3
    k_gemm<true><<<gemm_grid, 256, 0, stream>>>(Bb, W3, Hb);
    k_agg<<<agg_grid, 256, 0, stream>>>(Hb, off, csr, dinv2, b3, Ab);

    // pooling + classifier
    k_pool<<<N_GRAPHS, 256, 0, stream>>>(Ab, goff, Wl, bl, (float*)d_out);
}

// Round 5
// 430.754 us; speedup vs baseline: 5.1220x; 1.0713x over previous
//
#include <hip/hip_runtime.h>
#include <hip/hip_bf16.h>

#define N_NODES   100000
#define N_EDGES   1600000
#define F_IN      64
#define HID       64
#define N_CLASSES 45
#define N_GRAPHS  256
#define SB        98          // super-buckets: bucket = dst >> 10 (0..97)
#define CAP       17920       // fixed bucket capacity (mean 16327, sigma 127 -> +12 sigma)
#define CHUNK     8192        // edges per scatter workgroup
#define NCHUNK    196         // ceil(N_EDGES / CHUNK)

__device__ __forceinline__ float rl_f(float v, int k) {
    return __uint_as_float(__builtin_amdgcn_readlane(__float_as_uint(v), k));
}
__device__ __forceinline__ int rl_i(int v, int k) {
    return __builtin_amdgcn_readlane(v, k);
}

// ---------------- CSR build: bucket counting sort ----------------

// multisplit: stage 8192 edges in LDS by bucket, flush contiguous runs into
// fixed-capacity bucket regions (binned[b*CAP ...]). payload: src | dstLow<<17
__global__ __launch_bounds__(256) void k_scatter(const int* __restrict__ src, const int* __restrict__ dst,
                                                 int* __restrict__ bcur, int* __restrict__ binned) {
    __shared__ int stg[CHUNK];
    __shared__ int h[SB], lbase[SB], gbase[SB], cur[SB];
    __shared__ int ss[128];
    int t = threadIdx.x;
    if (t < SB) h[t] = 0;
    __syncthreads();
    int base4 = blockIdx.x * (CHUNK / 4);
    // phase 1: local histogram
    #pragma unroll
    for (int i = 0; i < CHUNK / 1024; i++) {
        int e4 = base4 + i * 256 + t;
        if (e4 < N_EDGES / 4) {
            int4 d = ((const int4*)dst)[e4];
            atomicAdd(&h[d.x >> 10], 1);
            atomicAdd(&h[d.y >> 10], 1);
            atomicAdd(&h[d.z >> 10], 1);
            atomicAdd(&h[d.w >> 10], 1);
        }
    }
    __syncthreads();
    // phase 2: local exclusive scan + global space reservation per bucket
    if (t < 128) ss[t] = (t < SB) ? h[t] : 0;
    __syncthreads();
    for (int o = 1; o < 128; o <<= 1) {
        int x = 0;
        if (t < 128 && t >= o) x = ss[t - o];
        __syncthreads();
        if (t < 128 && t >= o) ss[t] += x;
        __syncthreads();
    }
    if (t < SB) {
        int ex = ss[t] - h[t];
        lbase[t] = ex;
        cur[t]   = ex;
        gbase[t] = t * CAP + atomicAdd(&bcur[t], h[t]);
    }
    __syncthreads();
    // phase 3: re-read edges, scatter packed payload into LDS staging
    #pragma unroll
    for (int i = 0; i < CHUNK / 1024; i++) {
        int e4 = base4 + i * 256 + t;
        if (e4 < N_EDGES / 4) {
            int4 d  = ((const int4*)dst)[e4];
            int4 s4 = ((const int4*)src)[e4];
            int q;
            q = atomicAdd(&cur[d.x >> 10], 1); stg[q] = s4.x | ((d.x & 1023) << 17);
            q = atomicAdd(&cur[d.y >> 10], 1); stg[q] = s4.y | ((d.y & 1023) << 17);
            q = atomicAdd(&cur[d.z >> 10], 1); stg[q] = s4.z | ((d.z & 1023) << 17);
            q = atomicAdd(&cur[d.w >> 10], 1); stg[q] = s4.w | ((d.w & 1023) << 17);
        }
    }
    __syncthreads();
    // phase 4: flush each bucket's run contiguously (wave per bucket, round-robin)
    int wv = t >> 6, lane = t & 63;
    for (int b = wv; b < SB; b += 4) {
        int n = h[b], lb = lbase[b], gb = gbase[b];
        for (int i = lane; i < n; i += 64)
            binned[gb + i] = stg[lb + i];
    }
}

// per-bucket: degrees -> dinv/dinv2 + per-node csr ranges + fill csr (src only)
__global__ __launch_bounds__(256) void k_bcsr(const int* __restrict__ binned, const int* __restrict__ bcur,
                                              int2* __restrict__ range, float* __restrict__ dinv,
                                              float* __restrict__ dinv2, int* __restrict__ csr) {
    __shared__ int h[1024];
    __shared__ int ts[256];
    int t = threadIdx.x;
    int b = blockIdx.x;
    int nb0  = b << 10;
    int ebeg = b * CAP;
    int ecnt = bcur[b]; if (ecnt > CAP) ecnt = CAP;
    #pragma unroll
    for (int i = 0; i < 4; i++) h[t + i * 256] = 0;
    __syncthreads();
    // degree histogram over this bucket's edges
    for (int i = t; i < ecnt; i += 256)
        atomicAdd(&h[binned[ebeg + i] >> 17], 1);
    __syncthreads();
    int c0 = h[t * 4], c1 = h[t * 4 + 1], c2 = h[t * 4 + 2], c3 = h[t * 4 + 3];
    int tot = c0 + c1 + c2 + c3;
    ts[t] = tot;
    __syncthreads();
    for (int o = 1; o < 256; o <<= 1) {
        int x = (t >= o) ? ts[t - o] : 0;
        __syncthreads();
        if (t >= o) ts[t] += x;
        __syncthreads();
    }
    int ex = ts[t] - tot + ebeg;
    int n0 = nb0 + t * 4;
    int e0 = ex, e1 = ex + c0, e2 = e1 + c1, e3 = e2 + c2;
    if (n0 < N_NODES) {                  // bucket node-range is 4-aligned
        int eb[4] = { e0, e1, e2, e3 };
        int cc[4] = { c0, c1, c2, c3 };
        #pragma unroll
        for (int i = 0; i < 4; i++) {
            range[n0 + i] = make_int2(eb[i], eb[i] + cc[i]);
            float inv = 1.0f / (float)(cc[i] + 1);   // +1 self loop
            dinv2[n0 + i] = inv;
            dinv[n0 + i]  = sqrtf(inv);
        }
    }
    __syncthreads();
    // repurpose h[] as per-node write cursors
    h[t * 4] = e0; h[t * 4 + 1] = e1; h[t * 4 + 2] = e2; h[t * 4 + 3] = e3;
    __syncthreads();
    // fill csr (src index only; coef computed on-the-fly in k_agg)
    for (int i = t; i < ecnt; i += 256) {
        int p    = binned[ebeg + i];
        int dlow = p >> 17;
        int q = atomicAdd(&h[dlow], 1);
        csr[q] = p & 0x1FFFF;
    }
}

// ---------------- GEMM: H = relu?(in) @ W ----------------
template<bool RELU_IN>
__global__ __launch_bounds__(256, 4) void k_gemm(const float* __restrict__ in,
                                                 const float* __restrict__ W,
                                                 float* __restrict__ Hout) {
    int lane = threadIdx.x & 63;
    int wv   = threadIdx.x >> 6;
    float Wreg[64];
    #pragma unroll
    for (int k = 0; k < 64; k++) Wreg[k] = W[k * 64 + lane];

    int base = blockIdx.x * 32 + wv * 8;
    #pragma unroll 2
    for (int r = 0; r < 8; r++) {
        int row = base + r;                       // grid exact, no guard
        float xv = in[(size_t)row * 64 + lane];
        if (RELU_IN) xv = fmaxf(xv, 0.f);
        float acc = 0.f;
        #pragma unroll
        for (int k = 0; k < 64; k++)
            acc = fmaf(rl_f(xv, k), Wreg[k], acc);
        Hout[(size_t)row * 64 + lane] = acc;
    }
}

// ---------------- Aggregation (gather) ----------------
// A[i] = b + H[i]*dinv2[i] + dinv[i] * sum_j dinv[src_j] * H[src_j]
// one wave per node, lane = feature; 8 gathers in flight, 4 accumulators.
__global__ __launch_bounds__(256, 8) void k_agg(const float* __restrict__ Hbuf,
                                                const int2* __restrict__ range,
                                                const int* __restrict__ csr,
                                                const float* __restrict__ dinv,
                                                const float* __restrict__ dinv2,
                                                const float* __restrict__ bias,
                                                float* __restrict__ Abuf) {
    int wv   = threadIdx.x >> 6;
    int lane = threadIdx.x & 63;
    int node = blockIdx.x * 4 + wv;               // grid exact (25000*4)

    int2 r = range[node];
    int beg = r.x, end = r.y;
    float hself = Hbuf[(size_t)node * 64 + lane];
    float a0 = 0.f, a1 = 0.f, a2 = 0.f, a3 = 0.f;

    for (int cb = beg; cb < end; cb += 64) {
        int rem = end - cb; if (rem > 64) rem = 64;
        int ci = 0;
        if (lane < rem) ci = csr[cb + lane];
        float cs = dinv[ci];                      // per-lane 4B gather, L2-hot table
        int j = 0;
        for (; j + 8 <= rem; j += 8) {
            int   s0 = rl_i(ci, j),     s1 = rl_i(ci, j + 1);
            int   s2 = rl_i(ci, j + 2), s3 = rl_i(ci, j + 3);
            int   s4 = rl_i(ci, j + 4), s5 = rl_i(ci, j + 5);
            int   s6 = rl_i(ci, j + 6), s7 = rl_i(ci, j + 7);
            float c0 = rl_f(cs, j),     c1 = rl_f(cs, j + 1);
            float c2 = rl_f(cs, j + 2), c3 = rl_f(cs, j + 3);
            float c4 = rl_f(cs, j + 4), c5 = rl_f(cs, j + 5);
            float c6 = rl_f(cs, j + 6), c7 = rl_f(cs, j + 7);
            float h0 = Hbuf[(size_t)s0 * 64 + lane];
            float h1 = Hbuf[(size_t)s1 * 64 + lane];
            float h2 = Hbuf[(size_t)s2 * 64 + lane];
            float h3 = Hbuf[(size_t)s3 * 64 + lane];
            float h4 = Hbuf[(size_t)s4 * 64 + lane];
            float h5 = Hbuf[(size_t)s5 * 64 + lane];
            float h6 = Hbuf[(size_t)s6 * 64 + lane];
            float h7 = Hbuf[(size_t)s7 * 64 + lane];
            a0 = fmaf(h0, c0, a0);
            a1 = fmaf(h1, c1, a1);
            a2 = fmaf(h2, c2, a2);
            a3 = fmaf(h3, c3, a3);
            a0 = fmaf(h4, c4, a0);
            a1 = fmaf(h5, c5, a1);
            a2 = fmaf(h6, c6, a2);
            a3 = fmaf(h7, c7, a3);
        }
        for (; j + 2 <= rem; j += 2) {
            int   s0 = rl_i(ci, j),     s1 = rl_i(ci, j + 1);
            float c0 = rl_f(cs, j),     c1 = rl_f(cs, j + 1);
            float h0 = Hbuf[(size_t)s0 * 64 + lane];
            float h1 = Hbuf[(size_t)s1 * 64 + lane];
            a0 = fmaf(h0, c0, a0);
            a1 = fmaf(h1, c1, a1);
        }
        if (j < rem) {
            int   s0 = rl_i(ci, j);
            float c0 = rl_f(cs, j);
            a0 = fmaf(Hbuf[(size_t)s0 * 64 + lane], c0, a0);
        }
    }
    float esum = (a0 + a1) + (a2 + a3);
    float out  = fmaf(hself, dinv2[node], bias[lane]);
    Abuf[(size_t)node * 64 + lane] = fmaf(dinv[node], esum, out);
}

// ---------------- Pooling + classifier ----------------
// one block (16 waves) per graph; boundaries via binary search in sorted batch
__device__ __forceinline__ int lbound(const int* __restrict__ a, int n, int v) {
    int lo = 0, hi = n;
    while (lo < hi) { int m = (lo + hi) >> 1; if (a[m] < v) lo = m + 1; else hi = m; }
    return lo;
}

__global__ __launch_bounds__(1024) void k_pool(const float* __restrict__ A, const int* __restrict__ batch,
                                               const float* __restrict__ Wl, const float* __restrict__ bl,
                                               float* __restrict__ out) {
    __shared__ float red[16][64];
    __shared__ int bounds[2];
    int g    = blockIdx.x;
    int t    = threadIdx.x;
    int wv   = t >> 6;
    int lane = t & 63;
    if (t == 0) bounds[0] = lbound(batch, N_NODES, g);
    if (t == 1) bounds[1] = lbound(batch, N_NODES, g + 1);
    __syncthreads();
    int beg = bounds[0], end = bounds[1];

    float a0 = 0.f, a1 = 0.f;
    int i = beg + wv;
    for (; i + 16 < end; i += 32) {
        a0 += A[(size_t)i * 64 + lane];
        a1 += A[(size_t)(i + 16) * 64 + lane];
    }
    if (i < end) a0 += A[(size_t)i * 64 + lane];
    red[wv][lane] = a0 + a1;
    __syncthreads();
    if (wv == 0) {
        float s = 0.f;
        #pragma unroll
        for (int w = 0; w < 16; w++) s += red[w][lane];
        float cntf = (float)(end - beg);
        red[0][lane] = s / fmaxf(cntf, 1.0f);
    }
    __syncthreads();
    if (t < N_CLASSES) {
        float o = bl[t];
        #pragma unroll
        for (int k = 0; k < HID; k++) o = fmaf(red[0][k], Wl[k * N_CLASSES + t], o);
        out[g * N_CLASSES + t] = o;
    }
}

// ---------------- launch ----------------

extern "C" void kernel_launch(void* const* d_in, const int* in_sizes, int n_in,
                              void* d_out, int out_size, void* d_ws, size_t ws_size,
                              hipStream_t stream) {
    const float* x     = (const float*)d_in[0];
    const int*   eidx  = (const int*)  d_in[1];
    const int*   batch = (const int*)  d_in[2];
    const float* W1 = (const float*)d_in[3];
    const float* b1 = (const float*)d_in[4];
    const float* W2 = (const float*)d_in[5];
    const float* b2 = (const float*)d_in[6];
    const float* W3 = (const float*)d_in[7];
    const float* b3 = (const float*)d_in[8];
    const float* Wl = (const float*)d_in[9];
    const float* bl = (const float*)d_in[10];
    const int* src = eidx;
    const int* dst = eidx + N_EDGES;

    char* p = (char*)d_ws;
    auto alloc = [&](size_t bytes) -> void* {
        void* r = (void*)p;
        p += (bytes + 255) & ~(size_t)255;
        return r;
    };
    int2*  range = (int2*) alloc((size_t)N_NODES * 8);
    float* dinv  = (float*)alloc((size_t)N_NODES * 4);
    float* dinv2 = (float*)alloc((size_t)N_NODES * 4);
    int*   csr   = (int*)  alloc((size_t)SB * CAP * 4);
    float* Hb    = (float*)alloc((size_t)N_NODES * 64 * 4);
    float* Ab    = (float*)alloc((size_t)N_NODES * 64 * 4);
    float* Bb    = (float*)alloc((size_t)N_NODES * 64 * 4);
    int*   bcur  = (int*)  alloc((size_t)SB * 4);
    int*   binned = (int*)Hb;   // 7.0 MB scratch aliased onto Hb (dead after k_bcsr)

    const int gemm_grid = N_NODES / 32;            // 3125, exact
    const int agg_grid  = N_NODES / 4;             // 25000, exact

    // ---- CSR build: 3 dispatches ----
    hipMemsetAsync(bcur, 0, (size_t)SB * 4, stream);
    k_scatter<<<NCHUNK, 256, 0, stream>>>(src, dst, bcur, binned);
    k_bcsr   <<<SB, 256, 0, stream>>>(binned, bcur, range, dinv, dinv2, csr);

    // layer 1
    k_gemm<false><<<gemm_grid, 256, 0, stream>>>(x,  W1, Hb);
    k_agg<<<agg_grid, 256, 0, stream>>>(Hb, range, csr, dinv, dinv2, b1, Ab);
    // layer 2
    k_gemm<true><<<gemm_grid, 256, 0, stream>>>(Ab, W2, Hb);
    k_agg<<<agg_grid, 256, 0, stream>>>(Hb, range, csr, dinv, dinv2, b2, Bb);
    // layer 3
    k_gemm<true><<<gemm_grid, 256, 0, stream>>>(Bb, W3, Hb);
    k_agg<<<agg_grid, 256, 0, stream>>>(Hb, range, csr, dinv, dinv2, b3, Ab);

    // pooling + classifier
    k_pool<<<N_GRAPHS, 1024, 0, stream>>>(Ab, batch, Wl, bl, (float*)d_out);
}